// Round 10
// baseline (54.011 us; speedup 1.0000x reference)
//
#include <hip/hip_runtime.h>

#define B 64
#define T 512
#define E 512
#define H 64
#define NEG_INF (-1e30f)

// ---------------- projection GEMM params (unchanged) ----------------
#define PBM 64
#define PBK 64
#define PN 192
#define NCHK (E / PBK)

// q pre-scale: H^-0.5 * log2(e)  (scores land in log2 domain)
#define QSCALE 0.18033688011112043f
#define DEFER_THR 8.0f

using short8 = __attribute__((ext_vector_type(8))) short;
using f32x16 = __attribute__((ext_vector_type(16))) float;

__device__ __forceinline__ unsigned short f2bf(float f) {
    unsigned int u = __float_as_uint(f);
    u += 0x7fffu + ((u >> 16) & 1u);
    return (unsigned short)(u >> 16);
}
__device__ __forceinline__ unsigned int bfpack_tr(float lo, float hi) {
    return (__float_as_uint(hi) & 0xffff0000u) | (__float_as_uint(lo) >> 16);
}
__device__ __forceinline__ void async_copy16(const void* g, void* l) {
    __builtin_amdgcn_global_load_lds(
        (const __attribute__((address_space(1))) unsigned int*)g,
        (__attribute__((address_space(3))) unsigned int*)l, 16, 0, 0);
}

// ---------------------------------------------------------------------------
// Kernel 0: one-time prep (unchanged).
// ---------------------------------------------------------------------------
__global__ __launch_bounds__(256) void prep(
    const float* __restrict__ Wq, const float* __restrict__ Wk,
    const float* __restrict__ Wv, const int* __restrict__ am,
    unsigned short* __restrict__ WT_swz, unsigned int* __restrict__ mbits)
{
    const int bid = blockIdx.x;
    if (bid < 384) {
        const int i = bid * 256 + threadIdx.x;
        const int c   = i / (PN * 64);
        const int rem = i - c * (PN * 64);
        const int row = rem >> 6;
        const int s   = rem & 63;
        const int klocal = s ^ ((row & 7) << 3);
        const int k   = c * 64 + klocal;
        const int seg = row >> 6, hh = row & 63;
        const float* W = (seg == 0) ? Wq : (seg == 1) ? Wk : Wv;
        WT_swz[i] = f2bf(W[(size_t)k * H + hh]);
    } else {
        const int i = (bid - 384) * 256 + threadIdx.x;
        const unsigned long long bal = __ballot(am[i] != 0);
        const int lane = threadIdx.x & 63;
        if (lane == 0)       mbits[i >> 5] = (unsigned int)bal;
        else if (lane == 32) mbits[i >> 5] = (unsigned int)(bal >> 32);
    }
}

// ---------------------------------------------------------------------------
// Kernel 1: fused q/k/v projection GEMM, 2-phase dbuf pipeline.  Body
// unchanged; epilogue now scatters into MFMA-FRAGMENT layouts so the
// attention kernel's loads are perfectly coalesced (lane*16B):
//   qfrag/kfrag[(b*16+blk)*4+ks][lane][8]: elem(row kk,h): ks=h>>4,
//     lane=((h>>3)&1)*32+kk, e=h&7
//   vfrag[(b*16+blk)*4+fi][lane][8]: elem(key kk,h): fi=(kk>>4)*2+(h>>5),
//     lane=((kk>>3)&1)*32+(h&31), e=kk&7
// q is pre-scaled by QSCALE (log2-domain scores).
// ---------------------------------------------------------------------------
__global__ __launch_bounds__(256) void proj_gemm(
    const float* __restrict__ x,
    const unsigned short* __restrict__ WT_swz,
    unsigned short* __restrict__ qfrag, unsigned short* __restrict__ kfrag,
    unsigned short* __restrict__ vfrag)
{
    __shared__ unsigned short Xs[2][PBM * 64];
    __shared__ unsigned short Ws[2][PN * 64];

    const int tid  = threadIdx.x;
    const int wid  = tid >> 6;
    const int lane = tid & 63;
    const int hi   = lane >> 5;
    const int r    = lane & 31;
    const int row0 = blockIdx.x * PBM;

    const int mrow  = (wid >> 1) * 32 + r;
    const int cbase = (wid & 1) * 96;

    const int aBase = mrow * 128;
    const int aXor  = (mrow & 7) << 4;
    int bBase[3], bXor[3];
    #pragma unroll
    for (int nt = 0; nt < 3; ++nt) {
        const int col = cbase + nt * 32 + r;
        bBase[nt] = col * 128;
        bXor[nt]  = (col & 7) << 4;
    }
    const int xs_rr[2]  = { tid >> 3, (256 + tid) >> 3 };
    const int xs_s16[2] = { tid & 7, tid & 7 };

    f32x16 acc[3] = {};

    {
        #pragma unroll
        for (int p = 0; p < 6; ++p) {
            const int u = p * 256 + wid * 64 + lane;
            async_copy16(WT_swz + u * 8, (char*)(&Ws[0][0]) + (p * 256 + wid * 64) * 16);
        }
        #pragma unroll
        for (int p = 0; p < 2; ++p) {
            const int rr = xs_rr[p], s16 = xs_s16[p];
            const float4* src = reinterpret_cast<const float4*>(
                &x[(size_t)(row0 + rr) * E + s16 * 8]);
            const float4 a0 = src[0], a1 = src[1];
            union { unsigned short us[8]; short8 v; } pk;
            pk.us[0] = f2bf(a0.x); pk.us[1] = f2bf(a0.y);
            pk.us[2] = f2bf(a0.z); pk.us[3] = f2bf(a0.w);
            pk.us[4] = f2bf(a1.x); pk.us[5] = f2bf(a1.y);
            pk.us[6] = f2bf(a1.z); pk.us[7] = f2bf(a1.w);
            const int cb = (s16 * 16) ^ ((rr & 7) << 4);
            *reinterpret_cast<short8*>((char*)(&Xs[0][0]) + rr * 128 + cb) = pk.v;
        }
        __syncthreads();
    }

    for (int c = 0; c < NCHK; ++c) {
        const int cur = c & 1;
        const bool pre = (c + 1 < NCHK);
        float4 xa[2], xb[2];

        if (pre) {
            const unsigned short* gw = WT_swz + (size_t)(c + 1) * (PN * 64);
            #pragma unroll
            for (int p = 0; p < 6; ++p) {
                const int u = p * 256 + wid * 64 + lane;
                async_copy16(gw + u * 8,
                             (char*)(&Ws[cur ^ 1][0]) + (p * 256 + wid * 64) * 16);
            }
            const int kc = (c + 1) * PBK;
            #pragma unroll
            for (int p = 0; p < 2; ++p) {
                const float4* src = reinterpret_cast<const float4*>(
                    &x[(size_t)(row0 + xs_rr[p]) * E + kc + xs_s16[p] * 8]);
                xa[p] = src[0];
                xb[p] = src[1];
            }
        }

        #pragma unroll
        for (int ks = 0; ks < 4; ++ks) {
            const int koff = ks * 32 + hi * 16;
            const short8 a = *reinterpret_cast<const short8*>(
                (const char*)(&Xs[cur][0]) + aBase + (koff ^ aXor));
            #pragma unroll
            for (int nt = 0; nt < 3; ++nt) {
                const short8 b = *reinterpret_cast<const short8*>(
                    (const char*)(&Ws[cur][0]) + bBase[nt] + (koff ^ bXor[nt]));
                acc[nt] = __builtin_amdgcn_mfma_f32_32x32x16_bf16(a, b, acc[nt], 0, 0, 0);
            }
        }

        if (pre) {
            #pragma unroll
            for (int p = 0; p < 2; ++p) {
                const int rr = xs_rr[p], s16 = xs_s16[p];
                union { unsigned short us[8]; short8 v; } pk;
                pk.us[0] = f2bf(xa[p].x); pk.us[1] = f2bf(xa[p].y);
                pk.us[2] = f2bf(xa[p].z); pk.us[3] = f2bf(xa[p].w);
                pk.us[4] = f2bf(xb[p].x); pk.us[5] = f2bf(xb[p].y);
                pk.us[6] = f2bf(xb[p].z); pk.us[7] = f2bf(xb[p].w);
                const int cb = (s16 * 16) ^ ((rr & 7) << 4);
                *reinterpret_cast<short8*>((char*)(&Xs[cur ^ 1][0]) + rr * 128 + cb) = pk.v;
            }
        }
        __syncthreads();
    }

    // ---- epilogue: scatter into fragment layouts ----
    #pragma unroll
    for (int nt = 0; nt < 3; ++nt) {
        const int gc  = cbase + nt * 32 + r;
        const int seg = gc >> 6;
        const int h   = gc & 63;
        #pragma unroll
        for (int reg = 0; reg < 16; ++reg) {
            const int drow = (reg & 3) + 8 * (reg >> 2) + 4 * hi;
            const int grow = row0 + (wid >> 1) * 32 + drow;
            const float val = acc[nt][reg];
            const int bb  = grow >> 9;
            const int key = grow & 511;
            const int blk = key >> 5;
            const int kk  = key & 31;
            if (seg == 0) {
                qfrag[(((size_t)bb * 16 + blk) * 4 + (h >> 4)) * 512
                      + (((h >> 3) & 1) * 32 + kk) * 8 + (h & 7)] = f2bf(val * QSCALE);
            } else if (seg == 1) {
                kfrag[(((size_t)bb * 16 + blk) * 4 + (h >> 4)) * 512
                      + (((h >> 3) & 1) * 32 + kk) * 8 + (h & 7)] = f2bf(val);
            } else {
                vfrag[(((size_t)bb * 16 + blk) * 4 + ((kk >> 4) * 2 + (h >> 5))) * 512
                      + (((kk >> 3) & 1) * 32 + (h & 31)) * 8 + (kk & 7)] = f2bf(val);
            }
        }
    }
}

// ---------------------------------------------------------------------------
// Kernel 2: ONLINE flash attention, one wave per (batch, 32-row q strip).
// All Q/K/V loads are coalesced fragment loads (base + lane*16B).
// Scores in log2 domain (QSCALE folded in proj) -> bare v_exp_f32.
// Defer-max: skip O-rescale unless some row's max grew by > DEFER_THR.
// ---------------------------------------------------------------------------
__global__ __launch_bounds__(64) void attn_online(
    const unsigned short* __restrict__ qfrag,
    const unsigned short* __restrict__ kfrag,
    const unsigned short* __restrict__ vfrag,
    const unsigned int* __restrict__ mbits,
    float* __restrict__ out)
{
    const int lane = threadIdx.x;
    const int hi = lane >> 5, r = lane & 31;
    const int h4 = 4 * hi;

    // XCD packing: all 16 strips of a batch on one XCD; big strips first
    const int bid = blockIdx.x;
    const int k   = bid >> 3;
    const int b   = ((k >> 4) << 3) | (bid & 7);
    const int s   = 15 - (k & 15);
    const int t0  = s * 32;
    const int tq  = t0 + r;

    const int l8 = lane * 8;

    // Q fragments (pre-scaled by QSCALE in proj)
    short8 qf[4];
    {
        const unsigned short* qb = qfrag + (((size_t)b * 16 + s) * 4) * 512;
        #pragma unroll
        for (int ks = 0; ks < 4; ++ks)
            qf[ks] = *reinterpret_cast<const short8*>(qb + ks * 512 + l8);
    }

    f32x16 accO[2] = {};
    float m = -INFINITY, l = 0.f;

    // prologue: K and V fragments for block 0
    short8 kf[4], vb[4];
    {
        const unsigned short* kb = kfrag + ((size_t)b * 16) * 4 * 512;
        const unsigned short* vv = vfrag + ((size_t)b * 16) * 4 * 512;
        #pragma unroll
        for (int ks = 0; ks < 4; ++ks) {
            kf[ks] = *reinterpret_cast<const short8*>(kb + ks * 512 + l8);
            vb[ks] = *reinterpret_cast<const short8*>(vv + ks * 512 + l8);
        }
    }

    for (int j = 0; j <= s; ++j) {
        // prefetch next block's K/V fragments (coalesced)
        short8 kn[4], vn[4];
        if (j < s) {
            const unsigned short* kb = kfrag + (((size_t)b * 16 + j + 1) * 4) * 512;
            const unsigned short* vv = vfrag + (((size_t)b * 16 + j + 1) * 4) * 512;
            #pragma unroll
            for (int ks = 0; ks < 4; ++ks) {
                kn[ks] = *reinterpret_cast<const short8*>(kb + ks * 512 + l8);
                vn[ks] = *reinterpret_cast<const short8*>(vv + ks * 512 + l8);
            }
        }

        // ---- QK^T swapped: lane owns q-row t0+r; regs cover 16 keys ----
        f32x16 sc = {};
        #pragma unroll
        for (int ks = 0; ks < 4; ++ks)
            sc = __builtin_amdgcn_mfma_f32_32x32x16_bf16(kf[ks], qf[ks], sc, 0, 0, 0);

        // ---- mask ----
        const unsigned int mw = mbits[b * 16 + j];
        float cmax = -INFINITY;
        if (j == s) {   // diagonal block: causal + pad mask
            #pragma unroll
            for (int reg = 0; reg < 16; ++reg) {
                const int cr = (reg & 3) + 8 * (reg >> 2) + h4;
                float v = sc[reg];
                const bool bad = !((mw >> cr) & 1u) || (32 * j + cr > tq);
                v = bad ? NEG_INF : v;
                sc[reg] = v;
                cmax = fmaxf(cmax, v);
            }
        } else {        // full block: pad mask only
            #pragma unroll
            for (int reg = 0; reg < 16; ++reg) {
                const int cr = (reg & 3) + 8 * (reg >> 2) + h4;
                float v = sc[reg];
                v = ((mw >> cr) & 1u) ? v : NEG_INF;
                sc[reg] = v;
                cmax = fmaxf(cmax, v);
            }
        }
        cmax = fmaxf(cmax, __shfl_xor(cmax, 32));

        // ---- defer-max online update ----
        if (!__all(cmax <= m + DEFER_THR)) {
            const float m_new = fmaxf(m, cmax);
            const float scale = exp2f(m - m_new);   // exp2(-inf)=0 first block
            f32x16 scf;
            #pragma unroll
            for (int reg = 0; reg < 16; ++reg)
                scf[reg] = __shfl(scale, (reg & 3) + 8 * (reg >> 2) + h4);
            #pragma unroll
            for (int reg = 0; reg < 16; ++reg) {
                accO[0][reg] *= scf[reg];
                accO[1][reg] *= scf[reg];
            }
            l *= scale;
            m = m_new;
        }

        float csum = 0.f;
        #pragma unroll
        for (int reg = 0; reg < 16; ++reg) {
            const float p = exp2f(sc[reg] - m);     // bounded by 2^DEFER_THR
            sc[reg] = p;
            csum += p;
        }
        csum += __shfl_xor(csum, 32);
        l += csum;

        // ---- PV: build P bf16 A-frags in-register, accumulate ----
        unsigned int pk[8];
        #pragma unroll
        for (int jj = 0; jj < 8; ++jj)
            pk[jj] = bfpack_tr(sc[2 * jj], sc[2 * jj + 1]);
        #pragma unroll
        for (int hs = 0; hs < 2; ++hs) {
            const unsigned int p01 = pk[hs * 4 + 0], p23 = pk[hs * 4 + 1];
            const unsigned int p45 = pk[hs * 4 + 2], p67 = pk[hs * 4 + 3];
            const unsigned int sendA = hi ? p01 : p45;
            const unsigned int sendB = hi ? p23 : p67;
            const unsigned int recvA = (unsigned int)__shfl_xor((int)sendA, 32);
            const unsigned int recvB = (unsigned int)__shfl_xor((int)sendB, 32);
            union { unsigned int uu[4]; short8 s8; } aw;
            aw.uu[0] = hi ? recvA : p01;
            aw.uu[1] = hi ? recvB : p23;
            aw.uu[2] = hi ? p45 : recvA;
            aw.uu[3] = hi ? p67 : recvB;
            #pragma unroll
            for (int tile = 0; tile < 2; ++tile)
                accO[tile] = __builtin_amdgcn_mfma_f32_32x32x16_bf16(
                    aw.s8, vb[hs * 2 + tile], accO[tile], 0, 0, 0);
        }

        #pragma unroll
        for (int ks = 0; ks < 4; ++ks) { kf[ks] = kn[ks]; vb[ks] = vn[ks]; }
    }

    // ---- epilogue: normalize and store ----
    const float inv = 1.f / l;
    #pragma unroll
    for (int reg = 0; reg < 16; ++reg) {
        const int qrow = (reg & 3) + 8 * (reg >> 2) + h4;
        const float f = __shfl(inv, qrow);
        float* op = &out[((size_t)b * T + t0 + qrow) * H];
        op[r]      = accO[0][reg] * f;
        op[r + 32] = accO[1][reg] * f;
    }
}

// ---------------------------------------------------------------------------
extern "C" void kernel_launch(void* const* d_in, const int* in_sizes, int n_in,
                              void* d_out, int out_size, void* d_ws, size_t ws_size,
                              hipStream_t stream) {
    const float* x         = (const float*)d_in[0];
    const int*   attn_mask = (const int*)d_in[1];
    const float* Wk        = (const float*)d_in[2];
    const float* Wq        = (const float*)d_in[3];
    const float* Wv        = (const float*)d_in[4];
    float* out = (float*)d_out;

    unsigned short* qfrag  = (unsigned short*)d_ws;                      // 4 MB
    unsigned short* kfrag  = qfrag + (size_t)B * T * H;                  // 4 MB
    unsigned short* vfrag  = kfrag + (size_t)B * T * H;                  // 4 MB
    unsigned short* WT_swz = vfrag + (size_t)B * T * H;                  // 192 KB
    unsigned int*   mbits  = (unsigned int*)(WT_swz + (size_t)PN * E);   // 4 KB

    prep<<<512, 256, 0, stream>>>(Wq, Wk, Wv, attn_mask, WT_swz, mbits);
    proj_gemm<<<(B * T) / PBM, 256, 0, stream>>>(x, WT_swz, qfrag, kfrag, vfrag);
    attn_online<<<B * 16, 64, 0, stream>>>(qfrag, kfrag, vfrag, mbits, out);
}